// Round 7
// baseline (22.065 us; speedup 1.0000x reference)
//
#include <hip/hip_runtime.h>

// Fused single kernel, no LDS tile (j-stream is L2-resident), occupancy-fixed:
// TPB=256 with __launch_bounds__(256,4) => <=128 VGPR, 4 blocks/CU, grid=1024
// fully resident in one round (prev rounds: 512-thread blocks likely >128 VGPR
// => 1 block/CU => 2 sequential rounds at 2 waves/SIMD).
//   y = XX@W1^T + b1; standardize over all 2N elems (ddof=1) => only
//   c = log2e/var needed (mean cancels in pairwise differences).
//   kc = c*(r_i + r_j - 2 y_i.y_j) = log2e*K;  term = (-ln2/2*W2_j)*kc*2^kc.
// Inner per 2 pairs: 3 pk_fma + pk_mul + pk_fma + 2 v_exp_f32.
// Every block recomputes stats in identical fixed order -> deterministic.

#define NN   8192
#define TPB  256
#define RB   8               // rows per block (all threads share these rows)
#define NH   (RB / 2)        // 4 v2f row-groups
#define JPT  (NN / TPB)      // 32 j per thread
#define NWV  (TPB / 64)      // 4 waves per block

typedef float v2f __attribute__((ext_vector_type(2)));

#if __has_builtin(__builtin_amdgcn_exp2f)
#define EXP2(x) __builtin_amdgcn_exp2f(x)
#else
#define EXP2(x) exp2f(x)
#endif

__global__ __launch_bounds__(TPB, 4) void fused_kernel(
    const float2* __restrict__ XX, const float* __restrict__ W1,
    const float* __restrict__ b1, const float* __restrict__ W2,
    const float* __restrict__ b2, float* __restrict__ out)
{
    __shared__ float ls[NWV], lq[NWV];
    __shared__ float csh;
    __shared__ float wred[NWV][RB];

    int tid = threadIdx.x;
    float w00 = W1[0], w01 = W1[1], w10 = W1[2], w11 = W1[3];
    float b0 = b1[0], bb1 = b1[1];

    // --- stats partial (identical order in every block -> identical c) ---
    const float4* XX4 = (const float4*)XX;
    float s = 0.f, q = 0.f;
#pragma unroll
    for (int ii = 0; ii < (NN / 2) / TPB; ii++) {      // 16 unrolled iters
        float4 v = XX4[ii * TPB + tid];
        float y0 = fmaf(v.y, w01, fmaf(v.x, w00, b0));
        float y1 = fmaf(v.y, w11, fmaf(v.x, w10, bb1));
        float y2 = fmaf(v.w, w01, fmaf(v.z, w00, b0));
        float y3 = fmaf(v.w, w11, fmaf(v.z, w10, bb1));
        s += (y0 + y1) + (y2 + y3);
        q += fmaf(y0, y0, y1 * y1) + fmaf(y2, y2, y3 * y3);
    }
#pragma unroll
    for (int o = 32; o > 0; o >>= 1) {
        s += __shfl_xor(s, o, 64);
        q += __shfl_xor(q, o, 64);
    }
    int wv = tid >> 6;
    if ((tid & 63) == 0) { ls[wv] = s; lq[wv] = q; }
    __syncthreads();
    if (tid == 0) {
        float S = 0.f, Q = 0.f;
#pragma unroll
        for (int i = 0; i < NWV; i++) { S += ls[i]; Q += lq[i]; }
        float M = (float)(2 * NN);
        float var = (Q - S * S / M) / (M - 1.0f);   // ddof=1
        csh = 1.4426950408889634f / var;            // c = log2e / var
    }
    __syncthreads();
    float c = csh;

    // --- row registers: RB=8 rows per block, 4 v2f groups per thread ---
    int rowBase = blockIdx.x * RB;
    v2f A0p[NH], A1p[NH], Bp[NH], accp[NH];
    const v2f cp = {c, c};
    float m2c = -2.0f * c;
#pragma unroll
    for (int h = 0; h < NH; h++) {
        float2 xa = XX[rowBase + 2 * h];
        float2 xb = XX[rowBase + 2 * h + 1];
        float ya0 = fmaf(xa.y, w01, fmaf(xa.x, w00, b0));
        float ya1 = fmaf(xa.y, w11, fmaf(xa.x, w10, bb1));
        float yb0 = fmaf(xb.y, w01, fmaf(xb.x, w00, b0));
        float yb1 = fmaf(xb.y, w11, fmaf(xb.x, w10, bb1));
        A0p[h] = (v2f){m2c * ya0, m2c * yb0};
        A1p[h] = (v2f){m2c * ya1, m2c * yb1};
        Bp[h]  = (v2f){c * fmaf(ya0, ya0, ya1 * ya1), c * fmaf(yb0, yb0, yb1 * yb1)};
        accp[h] = (v2f){0.f, 0.f};
    }

    // --- main loop: j straight from global (L2-resident), no LDS, no barriers ---
#pragma unroll 2
    for (int k = 0; k < JPT; k++) {
        int j = k * TPB + tid;                 // lanes -> consecutive j: coalesced
        float2 xj = XX[j];
        float wj = W2[j];
        float y0 = fmaf(xj.y, w01, fmaf(xj.x, w00, b0));
        float y1 = fmaf(xj.y, w11, fmaf(xj.x, w10, bb1));
        float rj = fmaf(y0, y0, y1 * y1);
        float gw = -0.34657359027997264f * wj; // -(ln2)/2 * W2_j
        v2f qx = {y0, y0};
        v2f qy = {y1, y1};
        v2f qz = {rj, rj};
        v2f qw = {gw, gw};
#pragma unroll
        for (int h = 0; h < NH; h++) {
            v2f kc = __builtin_elementwise_fma(A0p[h], qx,
                     __builtin_elementwise_fma(A1p[h], qy,
                     __builtin_elementwise_fma(cp, qz, Bp[h])));
            v2f e;
            e.x = EXP2(kc.x);                  // v_exp_f32
            e.y = EXP2(kc.y);
            accp[h] = __builtin_elementwise_fma(qw * kc, e, accp[h]);
        }
    }

    // --- reduce: 256 threads all hold partials for the same 8 rows ---
#pragma unroll
    for (int h = 0; h < NH; h++) {
#pragma unroll
        for (int o = 1; o <= 32; o <<= 1) {
            accp[h].x += __shfl_xor(accp[h].x, o, 64);
            accp[h].y += __shfl_xor(accp[h].y, o, 64);
        }
    }
    if ((tid & 63) == 0) {
#pragma unroll
        for (int h = 0; h < NH; h++) {
            wred[wv][2 * h]     = accp[h].x;
            wred[wv][2 * h + 1] = accp[h].y;
        }
    }
    __syncthreads();
    if (tid < RB) {
        float sR = b2[0];
#pragma unroll
        for (int ww = 0; ww < NWV; ww++) sR += wred[ww][tid];
        out[rowBase + tid] = sR;
    }
}

extern "C" void kernel_launch(void* const* d_in, const int* in_sizes, int n_in,
                              void* d_out, int out_size, void* d_ws, size_t ws_size,
                              hipStream_t stream)
{
    const float* XX = (const float*)d_in[0];
    const float* W1 = (const float*)d_in[1];
    const float* b1 = (const float*)d_in[2];
    const float* W2 = (const float*)d_in[3];
    const float* b2 = (const float*)d_in[4];
    float* out = (float*)d_out;

    fused_kernel<<<NN / RB, TPB, 0, stream>>>((const float2*)XX, W1, b1, W2, b2, out);
}

// Round 8
// 20.246 us; speedup vs baseline: 1.0898x; 1.0898x over previous
//
#include <hip/hip_runtime.h>

// Fused single kernel, no LDS tile (j-stream is L2-resident).
// Round 7 = round 5 (best: RB=16 rows/block, TPB=512) + __launch_bounds__(512,4)
// to cap VGPR at 128 => 16 waves/CU => grid of 512 blocks fully resident
// (2 blocks/CU, 4 waves/SIMD) instead of 2 sequential rounds at 2 waves/SIMD.
//   y = XX@W1^T + b1; standardize over all 2N elems (ddof=1) => only
//   c = log2e/var needed (mean cancels in pairwise differences).
//   kc = c*(r_i + r_j - 2 y_i.y_j) = log2e*K;  term = (-ln2/2*W2_j)*kc*2^kc.
// Inner per 2 pairs: 3 pk_fma + pk_mul + pk_fma + 2 v_exp_f32.
// Every block recomputes stats in identical fixed order -> deterministic.

#define NN   8192
#define TPB  512
#define RB   16              // rows per block (all threads share these rows)
#define NH   (RB / 2)        // 8 v2f row-groups
#define JPT  (NN / TPB)      // 16 j per thread
#define NWV  (TPB / 64)      // 8 waves per block

typedef float v2f __attribute__((ext_vector_type(2)));

#if __has_builtin(__builtin_amdgcn_exp2f)
#define EXP2(x) __builtin_amdgcn_exp2f(x)
#else
#define EXP2(x) exp2f(x)
#endif

__global__ __launch_bounds__(TPB, 4) void fused_kernel(
    const float2* __restrict__ XX, const float* __restrict__ W1,
    const float* __restrict__ b1, const float* __restrict__ W2,
    const float* __restrict__ b2, float* __restrict__ out)
{
    __shared__ float ls[NWV], lq[NWV];
    __shared__ float csh;
    __shared__ float wred[NWV][RB];

    int tid = threadIdx.x;
    float w00 = W1[0], w01 = W1[1], w10 = W1[2], w11 = W1[3];
    float b0 = b1[0], bb1 = b1[1];

    // --- stats partial (identical order in every block -> identical c) ---
    const float4* XX4 = (const float4*)XX;
    float s = 0.f, q = 0.f;
#pragma unroll
    for (int ii = 0; ii < (NN / 2) / TPB; ii++) {      // 8 unrolled iters
        float4 v = XX4[ii * TPB + tid];
        float y0 = fmaf(v.y, w01, fmaf(v.x, w00, b0));
        float y1 = fmaf(v.y, w11, fmaf(v.x, w10, bb1));
        float y2 = fmaf(v.w, w01, fmaf(v.z, w00, b0));
        float y3 = fmaf(v.w, w11, fmaf(v.z, w10, bb1));
        s += (y0 + y1) + (y2 + y3);
        q += fmaf(y0, y0, y1 * y1) + fmaf(y2, y2, y3 * y3);
    }
#pragma unroll
    for (int o = 32; o > 0; o >>= 1) {
        s += __shfl_xor(s, o, 64);
        q += __shfl_xor(q, o, 64);
    }
    int wv = tid >> 6;
    if ((tid & 63) == 0) { ls[wv] = s; lq[wv] = q; }
    __syncthreads();
    if (tid == 0) {
        float S = 0.f, Q = 0.f;
#pragma unroll
        for (int i = 0; i < NWV; i++) { S += ls[i]; Q += lq[i]; }
        float M = (float)(2 * NN);
        float var = (Q - S * S / M) / (M - 1.0f);   // ddof=1
        csh = 1.4426950408889634f / var;            // c = log2e / var
    }
    __syncthreads();
    float c = csh;

    // --- row registers: RB=16 rows per block, 8 v2f groups per thread ---
    int rowBase = blockIdx.x * RB;
    v2f A0p[NH], A1p[NH], Bp[NH], accp[NH];
    const v2f cp = {c, c};
    float m2c = -2.0f * c;
#pragma unroll
    for (int h = 0; h < NH; h++) {
        float2 xa = XX[rowBase + 2 * h];
        float2 xb = XX[rowBase + 2 * h + 1];
        float ya0 = fmaf(xa.y, w01, fmaf(xa.x, w00, b0));
        float ya1 = fmaf(xa.y, w11, fmaf(xa.x, w10, bb1));
        float yb0 = fmaf(xb.y, w01, fmaf(xb.x, w00, b0));
        float yb1 = fmaf(xb.y, w11, fmaf(xb.x, w10, bb1));
        A0p[h] = (v2f){m2c * ya0, m2c * yb0};
        A1p[h] = (v2f){m2c * ya1, m2c * yb1};
        Bp[h]  = (v2f){c * fmaf(ya0, ya0, ya1 * ya1), c * fmaf(yb0, yb0, yb1 * yb1)};
        accp[h] = (v2f){0.f, 0.f};
    }

    // --- main loop: j straight from global (L2-resident), no LDS, no barriers ---
#pragma unroll 4
    for (int k = 0; k < JPT; k++) {
        int j = k * TPB + tid;                 // lanes -> consecutive j: coalesced
        float2 xj = XX[j];
        float wj = W2[j];
        float y0 = fmaf(xj.y, w01, fmaf(xj.x, w00, b0));
        float y1 = fmaf(xj.y, w11, fmaf(xj.x, w10, bb1));
        float rj = fmaf(y0, y0, y1 * y1);
        float gw = -0.34657359027997264f * wj; // -(ln2)/2 * W2_j
        v2f qx = {y0, y0};
        v2f qy = {y1, y1};
        v2f qz = {rj, rj};
        v2f qw = {gw, gw};
#pragma unroll
        for (int h = 0; h < NH; h++) {
            v2f kc = __builtin_elementwise_fma(A0p[h], qx,
                     __builtin_elementwise_fma(A1p[h], qy,
                     __builtin_elementwise_fma(cp, qz, Bp[h])));
            v2f e;
            e.x = EXP2(kc.x);                  // v_exp_f32
            e.y = EXP2(kc.y);
            accp[h] = __builtin_elementwise_fma(qw * kc, e, accp[h]);
        }
    }

    // --- reduce: 512 threads all hold partials for the same 16 rows ---
#pragma unroll
    for (int h = 0; h < NH; h++) {
#pragma unroll
        for (int o = 1; o <= 32; o <<= 1) {
            accp[h].x += __shfl_xor(accp[h].x, o, 64);
            accp[h].y += __shfl_xor(accp[h].y, o, 64);
        }
    }
    if ((tid & 63) == 0) {
#pragma unroll
        for (int h = 0; h < NH; h++) {
            wred[wv][2 * h]     = accp[h].x;
            wred[wv][2 * h + 1] = accp[h].y;
        }
    }
    __syncthreads();
    if (tid < RB) {
        float sR = b2[0];
#pragma unroll
        for (int ww = 0; ww < NWV; ww++) sR += wred[ww][tid];
        out[rowBase + tid] = sR;
    }
}

extern "C" void kernel_launch(void* const* d_in, const int* in_sizes, int n_in,
                              void* d_out, int out_size, void* d_ws, size_t ws_size,
                              hipStream_t stream)
{
    const float* XX = (const float*)d_in[0];
    const float* W1 = (const float*)d_in[1];
    const float* b1 = (const float*)d_in[2];
    const float* W2 = (const float*)d_in[3];
    const float* b2 = (const float*)d_in[4];
    float* out = (float*)d_out;

    fused_kernel<<<NN / RB, TPB, 0, stream>>>((const float2*)XX, W1, b1, W2, b2, out);
}